// Round 1
// baseline (521.187 us; speedup 1.0000x reference)
//
#include <hip/hip_runtime.h>
#include <hip/hip_bf16.h>

// Problem constants (CausalSelfAttention): D_MODEL=1024, H=16, Dh=64, B=4, T=2048
#define T_SEQ   2048
#define HEADS   16
#define DH      64
#define DMODEL  1024
#define EQKV    3072   // 3*H*Dh

typedef __attribute__((ext_vector_type(8))) __bf16  bf16x8;
typedef __attribute__((ext_vector_type(4))) float   f32x4;
typedef unsigned short ushort_t;
typedef unsigned int   uint_t;

__device__ __forceinline__ ushort_t f2bfu(float x) {
    union { float f; uint_t u; } c; c.f = x;
    uint_t u = c.u;
    uint_t r = (u + 0x7fffu + ((u >> 16) & 1u)) >> 16;
    return (ushort_t)r;
}

// ---------------------------------------------------------------------------
// fp32 -> bf16 conversion (vectorized float4 in, 4 bf16 out)
// ---------------------------------------------------------------------------
__global__ void cvt_f32_bf16(const float* __restrict__ in, ushort_t* __restrict__ out, int n4) {
    int i = blockIdx.x * blockDim.x + threadIdx.x;
    if (i >= n4) return;
    const float4 v = ((const float4*)in)[i];
    ushort_t r0 = f2bfu(v.x), r1 = f2bfu(v.y), r2 = f2bfu(v.z), r3 = f2bfu(v.w);
    uint_t lo = (uint_t)r0 | ((uint_t)r1 << 16);
    uint_t hi = (uint_t)r2 | ((uint_t)r3 << 16);
    ((uint2*)out)[i] = make_uint2(lo, hi);
}

// ---------------------------------------------------------------------------
// bf16 GEMM: C[M][N] = A[M][K] * Bt[N][K]^T   (both row-major bf16 raw ushort)
// 128x128 tile, BK=32, 256 threads = 4 waves in 2x2, each wave 64x64 (4x4 frags)
// ---------------------------------------------------------------------------
#define BM 128
#define BN 128
#define BK 32
#define LDPAD 8   // pad rows to 40 bf16 (80B) to break bank conflicts

template<bool OUT_BF16>
__global__ __launch_bounds__(256) void gemm_bt(const ushort_t* __restrict__ A,
                                               const ushort_t* __restrict__ Bt,
                                               void* __restrict__ Cv,
                                               int M, int N, int K) {
    __shared__ __align__(16) ushort_t As[BM][BK + LDPAD];
    __shared__ __align__(16) ushort_t Bs[BN][BK + LDPAD];

    const int tid  = threadIdx.x;
    const int bn   = blockIdx.x, bm = blockIdx.y;
    const int row0 = bm * BM, col0 = bn * BN;
    const int wid  = tid >> 6, lane = tid & 63;
    const int wr   = wid >> 1, wc = wid & 1;      // 2x2 wave grid
    const int lr   = lane & 15, lg = lane >> 4;

    f32x4 acc[4][4] = {};

    for (int k0 = 0; k0 < K; k0 += BK) {
        // stage A and B tiles: 512 chunks of 8 bf16 each, 2 per thread per matrix
        #pragma unroll
        for (int it = 0; it < 2; ++it) {
            int idx = tid + it * 256;     // 0..511
            int r   = idx >> 2;           // 0..127
            int kc  = (idx & 3) * 8;
            *(bf16x8*)&As[r][kc] = *(const bf16x8*)&A [(size_t)(row0 + r) * K + k0 + kc];
            *(bf16x8*)&Bs[r][kc] = *(const bf16x8*)&Bt[(size_t)(col0 + r) * K + k0 + kc];
        }
        __syncthreads();

        bf16x8 bfr[4];
        #pragma unroll
        for (int n = 0; n < 4; ++n)
            bfr[n] = *(const bf16x8*)&Bs[wc * 64 + n * 16 + lr][lg * 8];
        #pragma unroll
        for (int m = 0; m < 4; ++m) {
            bf16x8 a = *(const bf16x8*)&As[wr * 64 + m * 16 + lr][lg * 8];
            #pragma unroll
            for (int n = 0; n < 4; ++n)
                acc[m][n] = __builtin_amdgcn_mfma_f32_16x16x32_bf16(a, bfr[n], acc[m][n], 0, 0, 0);
        }
        __syncthreads();
    }

    // epilogue: C row = row0+wr*64+m*16+lg*4+i ; col = col0+wc*64+n*16+lr
    #pragma unroll
    for (int m = 0; m < 4; ++m) {
        int rowb = row0 + wr * 64 + m * 16 + lg * 4;
        #pragma unroll
        for (int n = 0; n < 4; ++n) {
            int col = col0 + wc * 64 + n * 16 + lr;
            #pragma unroll
            for (int i = 0; i < 4; ++i) {
                if (OUT_BF16)
                    ((ushort_t*)Cv)[(size_t)(rowb + i) * N + col] = f2bfu(acc[m][n][i]);
                else
                    ((float*)Cv)[(size_t)(rowb + i) * N + col] = acc[m][n][i];
            }
        }
    }
}

// ---------------------------------------------------------------------------
// Causal flash attention over bf16 qkv buffer [B*T][3072].
// Q = cols [0,1024), K = [1024,2048), V = [2048,3072); head h at offset h*64.
// One block = 64 q rows of one (b,h); 4 waves x 16 rows. KV tiles of 64.
// Output y bf16 [B*T][1024] (b,t,h,dh layout).
// ---------------------------------------------------------------------------
#define QBLK 64
#define KVB  64

__global__ __launch_bounds__(256) void attn_fwd(const ushort_t* __restrict__ qkv,
                                                ushort_t* __restrict__ y) {
    const int bh = blockIdx.y;            // b*16 + h
    const int qt = blockIdx.x;            // q tile
    const int b  = bh >> 4, h = bh & 15;
    const int tid = threadIdx.x, wid = tid >> 6, lane = tid & 63;
    const int lr = lane & 15, lg = lane >> 4;

    __shared__ __align__(16) ushort_t Ks[KVB][DH + 8];        // 64 x 72
    __shared__ __align__(16) ushort_t Vt[DH][KVB + 8];        // transposed V
    __shared__ __align__(16) ushort_t Pw[4][16][DH + 8];      // per-wave P

    const size_t rstride = EQKV;
    const int qbase = qt * QBLK + wid * 16;

    // Q fragments (A operand): row = qbase+lr, k = lg*8+j (+32)
    bf16x8 qf[2];
    {
        const ushort_t* qrow = qkv + ((size_t)(b * T_SEQ) + qbase + lr) * rstride + h * DH;
        qf[0] = *(const bf16x8*)&qrow[lg * 8];
        qf[1] = *(const bf16x8*)&qrow[lg * 8 + 32];
    }

    float mrow[4], lsum[4];
    f32x4 o[4] = {};
    #pragma unroll
    for (int i = 0; i < 4; ++i) { mrow[i] = -1e30f; lsum[i] = 0.f; }

    const int ntiles = qt + 1;            // causal: kv tiles 0..qt
    for (int t = 0; t < ntiles; ++t) {
        // ---- stage K tile + transposed V tile ----
        {
            int r = tid >> 3;             // 0..31
            int c = (tid & 7) * 8;        // 0..56
            #pragma unroll
            for (int it = 0; it < 2; ++it) {
                int kvr = r + it * 32;
                const size_t rowoff = ((size_t)(b * T_SEQ) + t * KVB + kvr) * rstride + h * DH;
                *(bf16x8*)&Ks[kvr][c] = *(const bf16x8*)&qkv[rowoff + 1024 + c];
                bf16x8 v = *(const bf16x8*)&qkv[rowoff + 2048 + c];
                #pragma unroll
                for (int j = 0; j < 8; ++j) Vt[c + j][kvr] = ((ushort_t*)&v)[j];
            }
        }
        __syncthreads();

        // ---- S = Q K^T (16 q x 64 kv), 4 col-frags, k=64 via 2 mfma ----
        f32x4 s[4];
        #pragma unroll
        for (int n = 0; n < 4; ++n) {
            f32x4 a = {};
            bf16x8 b0 = *(const bf16x8*)&Ks[n * 16 + lr][lg * 8];
            bf16x8 b1 = *(const bf16x8*)&Ks[n * 16 + lr][lg * 8 + 32];
            a = __builtin_amdgcn_mfma_f32_16x16x32_bf16(qf[0], b0, a, 0, 0, 0);
            a = __builtin_amdgcn_mfma_f32_16x16x32_bf16(qf[1], b1, a, 0, 0, 0);
            s[n] = a;
        }

        // ---- scale + causal mask + row max ----
        float pmax[4];
        #pragma unroll
        for (int i = 0; i < 4; ++i) pmax[i] = -1e30f;
        #pragma unroll
        for (int n = 0; n < 4; ++n) {
            int kvg = t * KVB + n * 16 + lr;
            #pragma unroll
            for (int i = 0; i < 4; ++i) {
                int qg = qbase + lg * 4 + i;
                float v = (kvg <= qg) ? s[n][i] * 0.125f : -1e30f;
                s[n][i] = v;
                pmax[i] = fmaxf(pmax[i], v);
            }
        }
        #pragma unroll
        for (int i = 0; i < 4; ++i) {
            float v = pmax[i];
            v = fmaxf(v, __shfl_xor(v, 1));
            v = fmaxf(v, __shfl_xor(v, 2));
            v = fmaxf(v, __shfl_xor(v, 4));
            v = fmaxf(v, __shfl_xor(v, 8));
            pmax[i] = v;
        }

        // ---- online softmax update + write P (bf16) to LDS ----
        float rsum[4];
        #pragma unroll
        for (int i = 0; i < 4; ++i) {
            float mnew = fmaxf(mrow[i], pmax[i]);
            float corr = __expf(mrow[i] - mnew);
            mrow[i] = mnew;
            lsum[i] *= corr;
            #pragma unroll
            for (int n = 0; n < 4; ++n) o[n][i] *= corr;
            rsum[i] = 0.f;
        }
        #pragma unroll
        for (int n = 0; n < 4; ++n) {
            #pragma unroll
            for (int i = 0; i < 4; ++i) {
                float p = __expf(s[n][i] - mrow[i]);
                rsum[i] += p;
                Pw[wid][lg * 4 + i][n * 16 + lr] = f2bfu(p);
            }
        }
        #pragma unroll
        for (int i = 0; i < 4; ++i) {
            float v = rsum[i];
            v += __shfl_xor(v, 1);
            v += __shfl_xor(v, 2);
            v += __shfl_xor(v, 4);
            v += __shfl_xor(v, 8);
            lsum[i] += v;
        }
        __syncthreads();   // P visible (and Ks/Vt reads done before restage later)

        // ---- O += P V : A=P (row=q=lr, k=kv), B=V^T tile (col=dh, k=kv) ----
        #pragma unroll
        for (int ks = 0; ks < 2; ++ks) {
            bf16x8 pa = *(const bf16x8*)&Pw[wid][lr][ks * 32 + lg * 8];
            #pragma unroll
            for (int n = 0; n < 4; ++n) {
                bf16x8 vb = *(const bf16x8*)&Vt[n * 16 + lr][ks * 32 + lg * 8];
                o[n] = __builtin_amdgcn_mfma_f32_16x16x32_bf16(pa, vb, o[n], 0, 0, 0);
            }
        }
        __syncthreads();   // before next tile overwrites Ks/Vt
    }

    // ---- normalize + store y (bf16), rows = qbase+lg*4+i, col = h*64+n*16+lr
    #pragma unroll
    for (int i = 0; i < 4; ++i) {
        float inv = 1.f / lsum[i];
        int q = qbase + lg * 4 + i;
        ushort_t* yrow = y + ((size_t)(b * T_SEQ) + q) * (HEADS * DH) + h * DH;
        #pragma unroll
        for (int n = 0; n < 4; ++n)
            yrow[n * 16 + lr] = f2bfu(o[n][i] * inv);
    }
}

// ---------------------------------------------------------------------------
// launch
// ---------------------------------------------------------------------------
extern "C" void kernel_launch(void* const* d_in, const int* in_sizes, int n_in,
                              void* d_out, int out_size, void* d_ws, size_t ws_size,
                              hipStream_t stream) {
    const float* x     = (const float*)d_in[0];   // [B*T, 1024]
    const float* w_qkv = (const float*)d_in[1];   // [3072, 1024]
    const float* w_out = (const float*)d_in[2];   // [1024, 1024]
    float* out = (float*)d_out;                   // [B*T, 1024]

    const int BT = 4 * T_SEQ;                     // 8192

    // workspace layout (bytes)
    char* ws = (char*)d_ws;
    ushort_t* xb   = (ushort_t*)(ws);                                   // 16.78 MB
    ushort_t* wqb  = (ushort_t*)(ws + 16777216);                        //  6.29 MB
    ushort_t* wob  = (ushort_t*)(ws + 16777216 + 6291456);              //  2.10 MB
    ushort_t* qkvb = (ushort_t*)(ws + 16777216 + 6291456 + 2097152);    // 50.33 MB
    ushort_t* yb   = (ushort_t*)(ws + 16777216 + 6291456 + 2097152 + 50331648); // 16.78 MB
    // total ~92.3 MB — assumed <= ws_size

    // 1) convert inputs to bf16
    {
        int n4 = (BT * DMODEL) / 4;
        cvt_f32_bf16<<<(n4 + 255) / 256, 256, 0, stream>>>(x, xb, n4);
        n4 = (EQKV * DMODEL) / 4;
        cvt_f32_bf16<<<(n4 + 255) / 256, 256, 0, stream>>>(w_qkv, wqb, n4);
        n4 = (DMODEL * DMODEL) / 4;
        cvt_f32_bf16<<<(n4 + 255) / 256, 256, 0, stream>>>(w_out, wob, n4);
    }

    // 2) qkv = x @ w_qkv^T   (M=8192, N=3072, K=1024) -> bf16
    {
        dim3 grid(EQKV / BN, BT / BM);
        gemm_bt<true><<<grid, 256, 0, stream>>>(xb, wqb, (void*)qkvb, BT, EQKV, DMODEL);
    }

    // 3) flash attention -> y bf16 [BT][1024]
    {
        dim3 grid(T_SEQ / QBLK, 4 * HEADS);
        attn_fwd<<<grid, 256, 0, stream>>>(qkvb, yb);
    }

    // 4) out = y @ w_out^T   (M=8192, N=1024, K=1024) -> fp32
    {
        dim3 grid(DMODEL / BN, BT / BM);
        gemm_bt<false><<<grid, 256, 0, stream>>>(yb, wob, d_out, BT, DMODEL, DMODEL);
    }
}

// Round 3
// 371.472 us; speedup vs baseline: 1.4030x; 1.4030x over previous
//
#include <hip/hip_runtime.h>
#include <hip/hip_bf16.h>

// Problem constants (CausalSelfAttention): D_MODEL=1024, H=16, Dh=64, B=4, T=2048
#define T_SEQ   2048
#define HEADS   16
#define DH      64
#define DMODEL  1024
#define EQKV    3072   // 3*H*Dh

typedef __attribute__((ext_vector_type(8)))  __bf16 bf16x8;
typedef __attribute__((ext_vector_type(4)))  float  f32x4;
typedef __attribute__((ext_vector_type(16))) float  f32x16;
typedef unsigned short ushort_t;
typedef unsigned int   uint_t;

__device__ __forceinline__ ushort_t f2bfu(float x) {
    union { float f; uint_t u; } c; c.f = x;
    uint_t u = c.u;
    uint_t r = (u + 0x7fffu + ((u >> 16) & 1u)) >> 16;
    return (ushort_t)r;
}

// pack 2 f32 -> u32 holding 2 bf16 (lo = first arg)
__device__ __forceinline__ uint_t cvtpk(float lo, float hi) {
    uint_t r;
    asm volatile("v_cvt_pk_bf16_f32 %0, %1, %2" : "=v"(r) : "v"(lo), "v"(hi));
    return r;
}

// ---------------------------------------------------------------------------
// fp32 -> bf16 conversion (vectorized float4 in, 4 bf16 out)
// ---------------------------------------------------------------------------
__global__ void cvt_f32_bf16(const float* __restrict__ in, ushort_t* __restrict__ out, int n4) {
    int i = blockIdx.x * blockDim.x + threadIdx.x;
    if (i >= n4) return;
    const float4 v = ((const float4*)in)[i];
    ushort_t r0 = f2bfu(v.x), r1 = f2bfu(v.y), r2 = f2bfu(v.z), r3 = f2bfu(v.w);
    uint_t lo = (uint_t)r0 | ((uint_t)r1 << 16);
    uint_t hi = (uint_t)r2 | ((uint_t)r3 << 16);
    ((uint2*)out)[i] = make_uint2(lo, hi);
}

// ---------------------------------------------------------------------------
// bf16 GEMM: C[M][N] = A[M][K] * Bt[N][K]^T   (row-major bf16 raw ushort)
// 128x128 tile, BK=32, 256 threads = 4 waves in 2x2, each wave 64x64 (4x4 frags)
// (unchanged from round 1 — known-correct)
// ---------------------------------------------------------------------------
#define BM 128
#define BN 128
#define BK 32
#define LDPAD 8

template<bool OUT_BF16>
__global__ __launch_bounds__(256) void gemm_bt(const ushort_t* __restrict__ A,
                                               const ushort_t* __restrict__ Bt,
                                               void* __restrict__ Cv,
                                               int M, int N, int K) {
    __shared__ __align__(16) ushort_t As[BM][BK + LDPAD];
    __shared__ __align__(16) ushort_t Bs[BN][BK + LDPAD];

    const int tid  = threadIdx.x;
    const int bn   = blockIdx.x, bm = blockIdx.y;
    const int row0 = bm * BM, col0 = bn * BN;
    const int wid  = tid >> 6, lane = tid & 63;
    const int wr   = wid >> 1, wc = wid & 1;
    const int lr   = lane & 15, lg = lane >> 4;

    f32x4 acc[4][4] = {};

    for (int k0 = 0; k0 < K; k0 += BK) {
        #pragma unroll
        for (int it = 0; it < 2; ++it) {
            int idx = tid + it * 256;
            int r   = idx >> 2;
            int kc  = (idx & 3) * 8;
            *(bf16x8*)&As[r][kc] = *(const bf16x8*)&A [(size_t)(row0 + r) * K + k0 + kc];
            *(bf16x8*)&Bs[r][kc] = *(const bf16x8*)&Bt[(size_t)(col0 + r) * K + k0 + kc];
        }
        __syncthreads();

        bf16x8 bfr[4];
        #pragma unroll
        for (int n = 0; n < 4; ++n)
            bfr[n] = *(const bf16x8*)&Bs[wc * 64 + n * 16 + lr][lg * 8];
        #pragma unroll
        for (int m = 0; m < 4; ++m) {
            bf16x8 a = *(const bf16x8*)&As[wr * 64 + m * 16 + lr][lg * 8];
            #pragma unroll
            for (int n = 0; n < 4; ++n)
                acc[m][n] = __builtin_amdgcn_mfma_f32_16x16x32_bf16(a, bfr[n], acc[m][n], 0, 0, 0);
        }
        __syncthreads();
    }

    #pragma unroll
    for (int m = 0; m < 4; ++m) {
        int rowb = row0 + wr * 64 + m * 16 + lg * 4;
        #pragma unroll
        for (int n = 0; n < 4; ++n) {
            int col = col0 + wc * 64 + n * 16 + lr;
            #pragma unroll
            for (int i = 0; i < 4; ++i) {
                if (OUT_BF16)
                    ((ushort_t*)Cv)[(size_t)(rowb + i) * N + col] = f2bfu(acc[m][n][i]);
                else
                    ((float*)Cv)[(size_t)(rowb + i) * N + col] = acc[m][n][i];
            }
        }
    }
}

// ---------------------------------------------------------------------------
// Causal flash attention, swapped-QK^T 32x32x16 structure.
// One block = 128 q rows of one (b,h); 4 waves x 32 q rows. KV tiles of 64.
// Per lane: one q column (i = lane&31); lane>>5 selects k-half of fragments.
// S^T = mfma(K, Q): C col = q, row = kv -> P lane-local; softmax in-register.
// PV: O^T = mfma(V^T, P^T): V^T staged transposed in LDS with chunk-XOR
// swizzle (conflict-free write AND read); P^T frags built via cvt_pk +
// shfl_xor(32). Staging software-pipelined (load regs early, write late).
// ---------------------------------------------------------------------------
__global__ __launch_bounds__(256, 3) void attn_fwd(const ushort_t* __restrict__ qkv,
                                                   ushort_t* __restrict__ y) {
    const int bh = blockIdx.y;            // b*16 + h
    const int bx = blockIdx.x;            // q block of 128
    const int b  = bh >> 4, h = bh & 15;
    const int tid = threadIdx.x, wid = tid >> 6, lane = tid & 63;
    const int i  = lane & 31;             // q column within warp tile
    const int hh = lane >> 5;             // k-half selector
    const int bT = b * T_SEQ;

    __shared__ __align__(16) ushort_t Ks[64][72];   // [kv][dh]
    __shared__ __align__(16) ushort_t Vt[64][72];   // [dh][kv], kv-chunk XOR-swizzled by dh>>3

    const int q0 = bx * 128 + wid * 32;
    const int qg = q0 + i;

    // Q B-fragments: col=q (lane&31), k=dh = kd*16 + hh*8 + j
    bf16x8 qf[4];
    {
        const ushort_t* qrow = qkv + (size_t)(bT + qg) * EQKV + h * DH;
        #pragma unroll
        for (int kd = 0; kd < 4; ++kd)
            qf[kd] = *(const bf16x8*)&qrow[kd * 16 + hh * 8];
    }

    // staging coords: thread -> (kv row sr(+32), dh chunk sc)
    const int sr = tid >> 3;              // 0..31
    const int sc = (tid & 7) * 8;         // 0..56

    float m = -1e30f, lsum = 0.f;
    f32x16 o0 = {}, o1 = {};

    const int nt = 2 * bx + 2;            // kv tiles 0..nt-1

    // ---- stage tile 0 directly ----
    #pragma unroll
    for (int it = 0; it < 2; ++it) {
        int r = sr + 32 * it;
        const size_t go = (size_t)(bT + r) * EQKV + h * DH + sc;
        uint4 kk = *(const uint4*)&qkv[go + 1024];
        uint4 vv = *(const uint4*)&qkv[go + 2048];
        *(uint4*)&Ks[r][sc] = kk;
        const ushort_t* vs = (const ushort_t*)&vv;
        int chunk = r >> 3, br = r & 7;
        #pragma unroll
        for (int j = 0; j < 8; ++j) {
            int dh = sc + j;
            Vt[dh][((chunk ^ (dh >> 3)) << 3) | br] = vs[j];
        }
    }
    __syncthreads();

    for (int t = 0; t < nt; ++t) {
        const bool has_next = (t + 1 < nt);

        // prefetch next tile into registers (latency hidden under compute)
        uint4 kr[2], vr[2];
        if (has_next) {
            #pragma unroll
            for (int it = 0; it < 2; ++it) {
                const size_t go = (size_t)(bT + (t + 1) * 64 + sr + 32 * it) * EQKV + h * DH + sc;
                kr[it] = *(const uint4*)&qkv[go + 1024];
                vr[it] = *(const uint4*)&qkv[go + 2048];
            }
        }

        const int kmin = t * 64;
        const bool skip = kmin > q0 + 31;         // tile entirely above diagonal for this warp
        if (!skip) {
            const bool needmask = (kmin + 63) > q0;

            // ---- S^T = K * Q^T : two 32-kv groups, K-dim = dh (4 slices) ----
            f32x16 st[2] = {};
            #pragma unroll
            for (int kd = 0; kd < 4; ++kd) {
                bf16x8 ka0 = *(const bf16x8*)&Ks[i][kd * 16 + hh * 8];
                bf16x8 ka1 = *(const bf16x8*)&Ks[32 + i][kd * 16 + hh * 8];
                st[0] = __builtin_amdgcn_mfma_f32_32x32x16_bf16(ka0, qf[kd], st[0], 0, 0, 0);
                st[1] = __builtin_amdgcn_mfma_f32_32x32x16_bf16(ka1, qf[kd], st[1], 0, 0, 0);
            }

            // ---- mask + row max (row is lane-local + partner lane) ----
            float pm = -1e30f;
            #pragma unroll
            for (int g = 0; g < 2; ++g) {
                #pragma unroll
                for (int r = 0; r < 16; ++r) {
                    float v = st[g][r];
                    if (needmask) {
                        int kv = kmin + g * 32 + (r & 3) + 8 * (r >> 2) + 4 * hh;
                        v = (kv <= qg) ? v : -1e30f;
                        st[g][r] = v;
                    }
                    pm = fmaxf(pm, v);
                }
            }
            pm = fmaxf(pm, __shfl_xor(pm, 32));

            // ---- online softmax (scale 0.125 folded into exp) ----
            const float mnew = fmaxf(m, pm);
            const float corr = __expf((m - mnew) * 0.125f);
            m = mnew;
            float rs = 0.f;
            #pragma unroll
            for (int g = 0; g < 2; ++g) {
                #pragma unroll
                for (int r = 0; r < 16; ++r) {
                    float p = __expf((st[g][r] - m) * 0.125f);
                    st[g][r] = p;
                    rs += p;
                }
            }
            rs += __shfl_xor(rs, 32);
            lsum = lsum * corr + rs;
            #pragma unroll
            for (int r = 0; r < 16; ++r) { o0[r] *= corr; o1[r] *= corr; }

            // ---- O^T += V^T * P^T over 4 kv-slices of 16 ----
            #pragma unroll
            for (int ks = 0; ks < 4; ++ks) {
                const int g = ks >> 1, b0 = (ks & 1) * 8;
                uint_t w0 = cvtpk(st[g][b0 + 0], st[g][b0 + 1]);
                uint_t w1 = cvtpk(st[g][b0 + 2], st[g][b0 + 3]);
                uint_t w2 = cvtpk(st[g][b0 + 4], st[g][b0 + 5]);
                uint_t w3 = cvtpk(st[g][b0 + 6], st[g][b0 + 7]);
                uint_t e0 = (uint_t)__shfl_xor((int)w0, 32);
                uint_t e1 = (uint_t)__shfl_xor((int)w1, 32);
                uint_t e2 = (uint_t)__shfl_xor((int)w2, 32);
                uint_t e3 = (uint_t)__shfl_xor((int)w3, 32);
                union { uint_t u[4]; bf16x8 v; } fr;
                fr.u[0] = hh ? e2 : w0;
                fr.u[1] = hh ? e3 : w1;
                fr.u[2] = hh ? w2 : e0;
                fr.u[3] = hh ? w3 : e1;
                const int cp0 = (((2 * ks + hh) ^ (i >> 3)) << 3);
                const int cp1 = (((2 * ks + hh) ^ (4 + (i >> 3))) << 3);
                bf16x8 va0 = *(const bf16x8*)&Vt[i][cp0];
                bf16x8 va1 = *(const bf16x8*)&Vt[32 + i][cp1];
                o0 = __builtin_amdgcn_mfma_f32_32x32x16_bf16(va0, fr.v, o0, 0, 0, 0);
                o1 = __builtin_amdgcn_mfma_f32_32x32x16_bf16(va1, fr.v, o1, 0, 0, 0);
            }
        }

        // ---- write prefetched tile to LDS ----
        if (has_next) {
            __syncthreads();              // all LDS reads of tile t done
            #pragma unroll
            for (int it = 0; it < 2; ++it) {
                int r = sr + 32 * it;
                *(uint4*)&Ks[r][sc] = kr[it];
                const ushort_t* vs = (const ushort_t*)&vr[it];
                int chunk = r >> 3, br = r & 7;
                #pragma unroll
                for (int j = 0; j < 8; ++j) {
                    int dh = sc + j;
                    Vt[dh][((chunk ^ (dh >> 3)) << 3) | br] = vs[j];
                }
            }
            __syncthreads();              // tile t+1 ready
        }
    }

    // ---- epilogue: normalize, pack bf16, store ----
    const float inv = 1.f / lsum;
    ushort_t* yrow = y + (size_t)(bT + qg) * (HEADS * DH) + h * DH;
    #pragma unroll
    for (int df = 0; df < 2; ++df) {
        const f32x16 oo = df ? o1 : o0;
        #pragma unroll
        for (int q4 = 0; q4 < 4; ++q4) {
            uint_t w0 = cvtpk(oo[q4 * 4 + 0] * inv, oo[q4 * 4 + 1] * inv);
            uint_t w1 = cvtpk(oo[q4 * 4 + 2] * inv, oo[q4 * 4 + 3] * inv);
            uint2 pk = make_uint2(w0, w1);
            *(uint2*)&yrow[df * 32 + q4 * 8 + hh * 4] = pk;
        }
    }
}

// ---------------------------------------------------------------------------
// launch
// ---------------------------------------------------------------------------
extern "C" void kernel_launch(void* const* d_in, const int* in_sizes, int n_in,
                              void* d_out, int out_size, void* d_ws, size_t ws_size,
                              hipStream_t stream) {
    const float* x     = (const float*)d_in[0];   // [B*T, 1024]
    const float* w_qkv = (const float*)d_in[1];   // [3072, 1024]
    const float* w_out = (const float*)d_in[2];   // [1024, 1024]

    const int BT = 4 * T_SEQ;                     // 8192

    char* ws = (char*)d_ws;
    ushort_t* xb   = (ushort_t*)(ws);
    ushort_t* wqb  = (ushort_t*)(ws + 16777216);
    ushort_t* wob  = (ushort_t*)(ws + 16777216 + 6291456);
    ushort_t* qkvb = (ushort_t*)(ws + 16777216 + 6291456 + 2097152);
    ushort_t* yb   = (ushort_t*)(ws + 16777216 + 6291456 + 2097152 + 50331648);

    // 1) convert inputs to bf16
    {
        int n4 = (BT * DMODEL) / 4;
        cvt_f32_bf16<<<(n4 + 255) / 256, 256, 0, stream>>>(x, xb, n4);
        n4 = (EQKV * DMODEL) / 4;
        cvt_f32_bf16<<<(n4 + 255) / 256, 256, 0, stream>>>(w_qkv, wqb, n4);
        n4 = (DMODEL * DMODEL) / 4;
        cvt_f32_bf16<<<(n4 + 255) / 256, 256, 0, stream>>>(w_out, wob, n4);
    }

    // 2) qkv = x @ w_qkv^T   (M=8192, N=3072, K=1024) -> bf16
    {
        dim3 grid(EQKV / BN, BT / BM);
        gemm_bt<true><<<grid, 256, 0, stream>>>(xb, wqb, (void*)qkvb, BT, EQKV, DMODEL);
    }

    // 3) flash attention -> y bf16 [BT][1024]
    {
        dim3 grid(T_SEQ / 128, 4 * HEADS);
        attn_fwd<<<grid, 256, 0, stream>>>(qkvb, yb);
    }

    // 4) out = y @ w_out^T   (M=8192, N=1024, K=1024) -> fp32
    {
        dim3 grid(DMODEL / BN, BT / BM);
        gemm_bt<false><<<grid, 256, 0, stream>>>(yb, wob, d_out, BT, DMODEL, DMODEL);
    }
}